// Round 2
// baseline (9796.746 us; speedup 1.0000x reference)
//
#include <hip/hip_runtime.h>
#include <hip/hip_bf16.h>
#include <hip/hip_cooperative_groups.h>
#include <math.h>

namespace cg = cooperative_groups;

#define NTC 60      // nonterminals
#define TTC 120     // preterminals
#define SD  512     // state dim
#define VV  10000   // vocab
#define BB  128     // batch
#define NN  40      // sentence length
#define STRW (NN*BB*NTC)    // 307200
#define FINF __int_as_float(0x7f800000)

// ===========================================================================
// Small helpers
// ===========================================================================
__device__ inline float warp_max64(float v) {
#pragma unroll
    for (int off = 32; off > 0; off >>= 1) v = fmaxf(v, __shfl_xor(v, off));
    return v;
}
__device__ inline float warp_sum64(float v) {
#pragma unroll
    for (int off = 32; off > 0; off >>= 1) v += __shfl_xor(v, off);
    return v;
}
__device__ inline float dot4(float4 a, float4 b) {
    return a.x*b.x + a.y*b.y + a.z*b.z + a.w*b.w;
}

// ===========================================================================
// gemm1: C[t,s] = maybe_relu(sum_k A[t,k]*W[s,k] + bias[s]) + res + res2
// One output per thread. grid = ceil(M*Sout/256).
// ===========================================================================
__global__ __launch_bounds__(256) void gemm1(
    const float* __restrict__ A, const float* __restrict__ W,
    const float* __restrict__ bias, const float* __restrict__ res,
    const float* __restrict__ res2, float* __restrict__ C,
    int M, int Sout, int do_relu)
{
    int o = blockIdx.x * 256 + threadIdx.x;
    if (o >= M * Sout) return;
    int s = o % Sout, t = o / Sout;
    const float4* wr = (const float4*)(W + (size_t)s * SD);
    const float4* ar = (const float4*)(A + (size_t)t * SD);
    float a0 = 0.f, a1 = 0.f, a2 = 0.f, a3 = 0.f;
#pragma unroll 2
    for (int k = 0; k < SD/4; k += 4) {
        float4 w0 = wr[k], w1 = wr[k+1], w2 = wr[k+2], w3 = wr[k+3];
        float4 x0 = ar[k], x1 = ar[k+1], x2 = ar[k+2], x3 = ar[k+3];
        a0 += dot4(w0, x0); a1 += dot4(w1, x1);
        a2 += dot4(w2, x2); a3 += dot4(w3, x3);
    }
    float v = (a0 + a1) + (a2 + a3);
    if (bias) v += bias[s];
    if (do_relu) v = fmaxf(v, 0.f);
    if (res)  v += res[o];
    if (res2) v += res2[o];
    C[o] = v;
}

// ===========================================================================
// vocab2: logits[t,v] = sum_k g[t,k]*VE[k,v].
// grid = (20 v-tiles of 512, 10 t-tiles of 12), block 256.
// g tile staged in LDS (broadcast reads), float2 VE loads per lane.
// ===========================================================================
#define V_TT 12
__global__ __launch_bounds__(256) void vocab2(
    const float* __restrict__ g, const float* __restrict__ VE,
    float* __restrict__ logits)
{
    __shared__ float gs[V_TT * SD];   // 24 KB
    int tid = threadIdx.x;
    int t0 = blockIdx.y * V_TT;
    int v0 = blockIdx.x * 512 + tid * 2;

    const float4* gsrc = (const float4*)(g + (size_t)t0 * SD);
    float4* gdst = (float4*)gs;
#pragma unroll
    for (int i = 0; i < 6; ++i) gdst[tid + i*256] = gsrc[tid + i*256];
    __syncthreads();

    bool act = v0 < VV;   // v0 even, VV even -> v0+1 also valid
    float2 acc[V_TT];
#pragma unroll
    for (int t = 0; t < V_TT; ++t) acc[t] = make_float2(0.f, 0.f);

    for (int k = 0; k < SD; k += 4) {
        float2 ve0, ve1, ve2, ve3;
        if (act) {
            ve0 = *(const float2*)(VE + (size_t)(k+0)*VV + v0);
            ve1 = *(const float2*)(VE + (size_t)(k+1)*VV + v0);
            ve2 = *(const float2*)(VE + (size_t)(k+2)*VV + v0);
            ve3 = *(const float2*)(VE + (size_t)(k+3)*VV + v0);
        } else {
            ve0 = ve1 = ve2 = ve3 = make_float2(0.f, 0.f);
        }
#pragma unroll
        for (int t = 0; t < V_TT; ++t) {
            float4 gv = *(const float4*)(&gs[t*SD + k]);
            acc[t].x += gv.x*ve0.x + gv.y*ve1.x + gv.z*ve2.x + gv.w*ve3.x;
            acc[t].y += gv.x*ve0.y + gv.y*ve1.y + gv.z*ve2.y + gv.w*ve3.y;
        }
    }
    if (act) {
#pragma unroll
        for (int t = 0; t < V_TT; ++t)
            *(float2*)(logits + (size_t)(t0+t)*VV + v0) = acc[t];
    }
}

// ===========================================================================
// root log-softmax (one wave)
// ===========================================================================
__global__ __launch_bounds__(64) void root_kernel(
    const float* __restrict__ root_emb, const float* __restrict__ rse,
    float* __restrict__ root_ls)
{
    int lane = threadIdx.x;
    float acc = 0.f;
    if (lane < NTC) {
        const float4* rr = (const float4*)(rse + (size_t)lane * SD);
        const float4* re = (const float4*)root_emb;
        for (int k = 0; k < SD/4; ++k) acc += dot4(re[k], rr[k]);
    }
    float mx = warp_max64(lane < NTC ? acc : -FINF);
    float ssum = warp_sum64(lane < NTC ? __expf(acc - mx) : 0.f);
    if (lane < NTC) root_ls[lane] = acc - (mx + __logf(ssum));
}

// ===========================================================================
// softmax over axis 0 of leftS/rightS (180x60), writing TRANSPOSED prob mats:
//   mT[60][60]  = softmax(S)[:60].T     (left_m / right_m transposed)
//   pT[60][120] = softmax(S)[60:].T     (left_p / right_p transposed)
// blockIdx.x: 0=left, 1=right. lane = column q.
// ===========================================================================
__global__ __launch_bounds__(64) void softmax0T(
    const float* __restrict__ leftS, const float* __restrict__ rightS,
    float* __restrict__ lmT, float* __restrict__ rmT,
    float* __restrict__ lpT, float* __restrict__ rpT)
{
    const float* S = blockIdx.x ? rightS : leftS;
    float* mT = blockIdx.x ? rmT : lmT;
    float* pT = blockIdx.x ? rpT : lpT;
    int q = threadIdx.x;
    if (q >= NTC) return;
    float mx = -FINF;
    for (int r = 0; r < 180; ++r) mx = fmaxf(mx, S[r*NTC + q]);
    float ssum = 0.f;
    for (int r = 0; r < 180; ++r) ssum += __expf(S[r*NTC + q] - mx);
    float inv = 1.f / ssum;
    for (int r = 0; r < NTC; ++r)
        mT[q*NTC + r] = __expf(S[r*NTC + q] - mx) * inv;
    for (int r = NTC; r < 180; ++r)
        pT[q*TTC + (r - NTC)] = __expf(S[r*NTC + q] - mx) * inv;
}

// ===========================================================================
// Inside-algorithm device pieces (shared by cooperative kernel and fallback)
// ===========================================================================
__device__ inline void lse_row_dev(int t, int lane,
    const float* __restrict__ logits, float* __restrict__ lse)
{
    const float4* row = (const float4*)(logits + (size_t)t * VV);
    float mx = -FINF, sm = 0.f;
    for (int i = lane; i < VV/4; i += 64) {
        float4 v = row[i];
        float m4 = fmaxf(fmaxf(v.x, v.y), fmaxf(v.z, v.w));
        float nm = fmaxf(mx, m4);
        sm = sm * __expf(mx - nm)
           + __expf(v.x-nm) + __expf(v.y-nm) + __expf(v.z-nm) + __expf(v.w-nm);
        mx = nm;
    }
#pragma unroll
    for (int off = 32; off > 0; off >>= 1) {
        float om = __shfl_xor(mx, off), os = __shfl_xor(sm, off);
        float nm = fmaxf(mx, om);
        sm = sm * __expf(mx - nm) + os * __expf(om - nm);
        mx = nm;
    }
    if (lane == 0) lse[t] = mx + __logf(sm);
}

__device__ inline void init_cell_dev(int c, int lane,
    const float* __restrict__ logits, const float* __restrict__ lse,
    const int* __restrict__ word, const float* __restrict__ lpT,
    const float* __restrict__ rpT, float* __restrict__ Lc,
    float* __restrict__ Rc, float* sh)
{
    int b = c / NN, n = c % NN;
    int wd = word[c];
    float u0 = logits[(size_t)lane * VV + wd] - lse[lane];
    int t1 = lane + 64;
    float u1 = (t1 < TTC) ? logits[(size_t)t1 * VV + wd] - lse[t1] : -FINF;
    float M = warp_max64(fmaxf(u0, u1));
    sh[lane]      = __expf(u0 - M);
    sh[lane + 64] = (t1 < TTC) ? __expf(u1 - M) : 0.f;
    __syncthreads();
    if (lane < NTC) {
        const float4* lp = (const float4*)(lpT + lane * TTC);
        const float4* rp = (const float4*)(rpT + lane * TTC);
        float aL = 0.f, aR = 0.f;
#pragma unroll
        for (int i = 0; i < TTC/4; ++i) {
            float4 lv = lp[i], rv = rp[i];
            float e0 = sh[4*i], e1 = sh[4*i+1], e2 = sh[4*i+2], e3 = sh[4*i+3];
            aL += lv.x*e0 + lv.y*e1 + lv.z*e2 + lv.w*e3;
            aR += rv.x*e0 + rv.y*e1 + rv.z*e2 + rv.w*e3;
        }
        int o = ((NN + n) * BB + b) * NTC + lane;   // w=1 slab
        Lc[o] = __logf(aL) + M;
        Rc[o] = __logf(aR) + M;
    }
    __syncthreads();
}

__device__ inline void width_cell_dev(int c, int lane, int w,
    const float* __restrict__ lmT, const float* __restrict__ rmT,
    float* __restrict__ Lc, float* __restrict__ Rc,
    float* __restrict__ beta_top, float* e)
{
    int m = NN - w + 1;
    int j = c % m, b = c / m;
    int p = (lane < NTC) ? lane : (NTC - 1);
    const int lb = (j * BB + b) * NTC + p;
    const int rb = w * STRW + (j * BB + b) * NTC + p;
    const int DR = BB * NTC - STRW;     // negative stride for Rc diagonal

    float mx = -FINF, sm = 0.f;
    int k = 1;
    for (; k + 3 < w; k += 4) {
        float l0 = Lc[lb + (k  )*STRW], r0 = Rc[rb + (k  )*DR];
        float l1 = Lc[lb + (k+1)*STRW], r1 = Rc[rb + (k+1)*DR];
        float l2 = Lc[lb + (k+2)*STRW], r2 = Rc[rb + (k+2)*DR];
        float l3 = Lc[lb + (k+3)*STRW], r3 = Rc[rb + (k+3)*DR];
        float v0 = l0+r0, v1 = l1+r1, v2 = l2+r2, v3 = l3+r3;
        float mv = fmaxf(fmaxf(v0, v1), fmaxf(v2, v3));
        float nm = fmaxf(mx, mv);
        sm = sm * __expf(mx - nm)
           + __expf(v0-nm) + __expf(v1-nm) + __expf(v2-nm) + __expf(v3-nm);
        mx = nm;
    }
    for (; k < w; ++k) {
        float v = Lc[lb + k*STRW] + Rc[rb + k*DR];
        float nm = fmaxf(mx, v);
        sm = sm * __expf(mx - nm) + __expf(v - nm);
        mx = nm;
    }
    float beta = __logf(sm) + mx;

    if (w == NN) {
        if (lane < NTC) beta_top[b * NTC + lane] = beta;
        return;
    }
    float bm = warp_max64(lane < NTC ? beta : -FINF);
    e[lane] = (lane < NTC) ? __expf(beta - bm) : 0.f;
    __syncthreads();
    if (lane < NTC) {
        const float4* lm = (const float4*)(lmT + lane * NTC);
        const float4* rm = (const float4*)(rmT + lane * NTC);
        float aL = 0.f, aR = 0.f;
#pragma unroll
        for (int i = 0; i < NTC/4; ++i) {
            float4 lv = lm[i], rv = rm[i];
            float e0 = e[4*i], e1 = e[4*i+1], e2 = e[4*i+2], e3 = e[4*i+3];
            aL += lv.x*e0 + lv.y*e1 + lv.z*e2 + lv.w*e3;
            aR += rv.x*e0 + rv.y*e1 + rv.z*e2 + rv.w*e3;
        }
        int o = ((w * NN + j) * BB + b) * NTC + lane;
        Lc[o] = __logf(aL) + bm;
        Rc[o] = __logf(aR) + bm;
    }
    __syncthreads();
}

__device__ inline void part_cell_dev(int b, int lane,
    const float* __restrict__ beta_top, const float* __restrict__ root_ls,
    float* __restrict__ out)
{
    float v = (lane < NTC) ? root_ls[lane] + beta_top[b * NTC + lane] : -FINF;
    float mx = warp_max64(v);
    float s = warp_sum64(lane < NTC ? __expf(v - mx) : 0.f);
    if (lane == 0) out[b] = mx + __logf(s);
}

__device__ inline void mean_dev(int lane, float* out)
{
    float s = out[lane] + out[lane + 64];
    s = warp_sum64(s);
    if (lane == 0) out[BB] = -s / (float)BB;
}

// ===========================================================================
// Cooperative inside kernel: lse -> init -> 39 widths -> partition -> mean
// ===========================================================================
__global__ __launch_bounds__(64) void inside_coop(
    const float* __restrict__ logits, const int* __restrict__ word,
    const float* __restrict__ lmT, const float* __restrict__ rmT,
    const float* __restrict__ lpT, const float* __restrict__ rpT,
    const float* __restrict__ root_ls, float* __restrict__ lse,
    float* __restrict__ Lc, float* __restrict__ Rc,
    float* __restrict__ beta_top, float* __restrict__ out)
{
    cg::grid_group gg = cg::this_grid();
    __shared__ float sh[128];
    int lane = threadIdx.x;
    int nb = gridDim.x, bid = blockIdx.x;

    for (int t = bid; t < TTC; t += nb) lse_row_dev(t, lane, logits, lse);
    gg.sync();
    for (int c = bid; c < BB*NN; c += nb)
        init_cell_dev(c, lane, logits, lse, word, lpT, rpT, Lc, Rc, sh);
    gg.sync();
    for (int w = 2; w <= NN; ++w) {
        int cells = (NN - w + 1) * BB;
        for (int c = bid; c < cells; c += nb)
            width_cell_dev(c, lane, w, lmT, rmT, Lc, Rc, beta_top, sh);
        gg.sync();
    }
    for (int b = bid; b < BB; b += nb)
        part_cell_dev(b, lane, beta_top, root_ls, out);
    gg.sync();
    if (bid == 0) mean_dev(lane, out);
}

// ===========================================================================
// Fallback (non-cooperative) wrappers
// ===========================================================================
__global__ __launch_bounds__(64) void lse_k(
    const float* __restrict__ logits, float* __restrict__ lse)
{ lse_row_dev(blockIdx.x, threadIdx.x, logits, lse); }

__global__ __launch_bounds__(64) void init_k(
    const float* __restrict__ logits, const float* __restrict__ lse,
    const int* __restrict__ word, const float* __restrict__ lpT,
    const float* __restrict__ rpT, float* __restrict__ Lc, float* __restrict__ Rc)
{
    __shared__ float sh[128];
    init_cell_dev(blockIdx.x, threadIdx.x, logits, lse, word, lpT, rpT, Lc, Rc, sh);
}

__global__ __launch_bounds__(64) void width_k(int w,
    const float* __restrict__ lmT, const float* __restrict__ rmT,
    float* __restrict__ Lc, float* __restrict__ Rc, float* __restrict__ beta_top)
{
    __shared__ float sh[128];
    width_cell_dev(blockIdx.x, threadIdx.x, w, lmT, rmT, Lc, Rc, beta_top, sh);
}

__global__ __launch_bounds__(64) void part_k(
    const float* __restrict__ beta_top, const float* __restrict__ root_ls,
    float* __restrict__ out)
{ part_cell_dev(blockIdx.x, threadIdx.x, beta_top, root_ls, out); }

__global__ __launch_bounds__(64) void mean_k(float* out)
{ mean_dev(threadIdx.x, out); }

// ===========================================================================
extern "C" void kernel_launch(void* const* d_in, const int* in_sizes, int n_in,
                              void* d_out, int out_size, void* d_ws, size_t ws_size,
                              hipStream_t stream)
{
    const int*   word     = (const int*)  d_in[0];
    const float* root_emb = (const float*)d_in[1];
    const float* rse      = (const float*)d_in[2];   // (180, 512)
    const float* VE       = (const float*)d_in[3];   // (512, 10000)
    const float* W0       = (const float*)d_in[4];
    const float* b0       = (const float*)d_in[5];
    const float* W1       = (const float*)d_in[6];   // (3,512,512)
    const float* b1       = (const float*)d_in[7];
    const float* W2       = (const float*)d_in[8];
    const float* b2       = (const float*)d_in[9];
    const float* lW       = (const float*)d_in[10];
    const float* lb       = (const float*)d_in[11];
    const float* rW       = (const float*)d_in[12];
    const float* rb       = (const float*)d_in[13];
    const float* pW       = (const float*)d_in[14];
    const float* pb       = (const float*)d_in[15];

    float* ws = (float*)d_ws;
    size_t o = 0;
    float* logits  = ws + o; o += (size_t)TTC * VV;     // 1,200,000
    float* lse     = ws + o; o += 128;
    float* h       = ws + o; o += TTC * SD;
    float* u       = ws + o; o += TTC * SD;
    float* gbuf    = ws + o; o += TTC * SD;
    float* parent1 = ws + o; o += NTC * SD;
    float* leftH   = ws + o; o += 180 * SD;
    float* rightH  = ws + o; o += 180 * SD;
    float* leftS   = ws + o; o += 180 * NTC;
    float* rightS  = ws + o; o += 180 * NTC;
    float* lmT     = ws + o; o += NTC * NTC;
    float* rmT     = ws + o; o += NTC * NTC;
    float* lpT     = ws + o; o += NTC * TTC;
    float* rpT     = ws + o; o += NTC * TTC;
    float* root_ls = ws + o; o += 64;
    float* beta_top= ws + o; o += BB * NTC;
    float* Lc      = ws + o; o += (size_t)NN * NN * BB * NTC;
    float* Rc      = ws + o; o += (size_t)NN * NN * BB * NTC;

    const float* term_emb = rse + NTC * SD;

    // ---- grammar: term MLP chain (120x512 each) ----
    gemm1<<<240, 256, 0, stream>>>(term_emb, W0, b0, nullptr, nullptr, h, TTC, SD, 0);
    for (int i = 0; i < 3; ++i) {
        gemm1<<<240, 256, 0, stream>>>(h, W1 + (size_t)i*SD*SD, b1 + i*SD,
                                       nullptr, nullptr, u, TTC, SD, 1);
        if (i < 2)
            gemm1<<<240, 256, 0, stream>>>(u, W2 + (size_t)i*SD*SD, b2 + i*SD,
                                           h, nullptr, h, TTC, SD, 1);
        else
            gemm1<<<240, 256, 0, stream>>>(u, W2 + (size_t)2*SD*SD, b2 + 2*SD,
                                           h, term_emb, gbuf, TTC, SD, 1);
    }

    // ---- grammar: rules ----
    root_kernel<<<1, 64, 0, stream>>>(root_emb, rse, root_ls);
    gemm1<<<120, 256, 0, stream>>>(rse, pW, pb, rse, nullptr, parent1, NTC, SD, 1);
    gemm1<<<360, 256, 0, stream>>>(rse, lW, lb, rse, nullptr, leftH, 180, SD, 1);
    gemm1<<<360, 256, 0, stream>>>(rse, rW, rb, rse, nullptr, rightH, 180, SD, 1);
    gemm1<<<43, 256, 0, stream>>>(leftH,  parent1, nullptr, nullptr, nullptr, leftS,  180, NTC, 0);
    gemm1<<<43, 256, 0, stream>>>(rightH, parent1, nullptr, nullptr, nullptr, rightS, 180, NTC, 0);
    softmax0T<<<2, 64, 0, stream>>>(leftS, rightS, lmT, rmT, lpT, rpT);

    // ---- vocab projection ----
    vocab2<<<dim3(20, 10), 256, 0, stream>>>(gbuf, VE, logits);

    // ---- inside algorithm: cooperative, with fallback ----
    void* args[] = { (void*)&logits, (void*)&word, (void*)&lmT, (void*)&rmT,
                     (void*)&lpT, (void*)&rpT, (void*)&root_ls, (void*)&lse,
                     (void*)&Lc, (void*)&Rc, (void*)&beta_top, (void*)&d_out };
    hipError_t rc = hipLaunchCooperativeKernel((void*)inside_coop,
                        dim3(2048), dim3(64), args, 0, stream);
    if (rc != hipSuccess) {
        lse_k<<<TTC, 64, 0, stream>>>(logits, lse);
        init_k<<<BB*NN, 64, 0, stream>>>(logits, lse, word, lpT, rpT, Lc, Rc);
        for (int w = 2; w <= NN; ++w)
            width_k<<<(NN - w + 1) * BB, 64, 0, stream>>>(w, lmT, rmT, Lc, Rc, beta_top);
        part_k<<<BB, 64, 0, stream>>>(beta_top, root_ls, (float*)d_out);
        mean_k<<<1, 64, 0, stream>>>((float*)d_out);
    }
}

// Round 5
// 930.585 us; speedup vs baseline: 10.5275x; 10.5275x over previous
//
#include <hip/hip_runtime.h>
#include <hip/hip_bf16.h>
#include <math.h>

#define NTC 60      // nonterminals
#define TTC 120     // preterminals
#define SD  512     // state dim
#define VV  10000   // vocab
#define BB  128     // batch
#define NN  40      // sentence length
#define TB  (NN*NN*NTC)     // 96000 floats: per-b table size [w][j][p]
#define FINF __int_as_float(0x7f800000)

// ===========================================================================
__device__ inline float warp_max64(float v) {
#pragma unroll
    for (int off = 32; off > 0; off >>= 1) v = fmaxf(v, __shfl_xor(v, off));
    return v;
}
__device__ inline float warp_sum64(float v) {
#pragma unroll
    for (int off = 32; off > 0; off >>= 1) v += __shfl_xor(v, off);
    return v;
}
__device__ inline float dot4(float4 a, float4 b) {
    return a.x*b.x + a.y*b.y + a.z*b.z + a.w*b.w;
}

// ===========================================================================
// gemm1: C[t,s] = maybe_relu(sum_k A[t,k]*W[s,k] + bias[s]) + res + res2
// One output per thread. grid = ceil(M*Sout/256). K = 512 fixed.
// ===========================================================================
__global__ __launch_bounds__(256) void gemm1(
    const float* __restrict__ A, const float* __restrict__ W,
    const float* __restrict__ bias, const float* __restrict__ res,
    const float* __restrict__ res2, float* __restrict__ C,
    int M, int Sout, int do_relu)
{
    int o = blockIdx.x * 256 + threadIdx.x;
    if (o >= M * Sout) return;
    int s = o % Sout, t = o / Sout;
    const float4* wr = (const float4*)(W + (size_t)s * SD);
    const float4* ar = (const float4*)(A + (size_t)t * SD);
    float a0 = 0.f, a1 = 0.f, a2 = 0.f, a3 = 0.f;
#pragma unroll 2
    for (int k = 0; k < SD/4; k += 4) {
        float4 w0 = wr[k], w1 = wr[k+1], w2 = wr[k+2], w3 = wr[k+3];
        float4 x0 = ar[k], x1 = ar[k+1], x2 = ar[k+2], x3 = ar[k+3];
        a0 += dot4(w0, x0); a1 += dot4(w1, x1);
        a2 += dot4(w2, x2); a3 += dot4(w3, x3);
    }
    float v = (a0 + a1) + (a2 + a3);
    if (bias) v += bias[s];
    if (do_relu) v = fmaxf(v, 0.f);
    if (res)  v += res[o];
    if (res2) v += res2[o];
    C[o] = v;
}

// ===========================================================================
// vocab2: logits[t,v] = sum_k g[t,k]*VE[k,v].  grid (20, 10), block 256.
// ===========================================================================
#define V_TT 12
__global__ __launch_bounds__(256) void vocab2(
    const float* __restrict__ g, const float* __restrict__ VE,
    float* __restrict__ logits)
{
    __shared__ float gs[V_TT * SD];
    int tid = threadIdx.x;
    int t0 = blockIdx.y * V_TT;
    int v0 = blockIdx.x * 512 + tid * 2;

    const float4* gsrc = (const float4*)(g + (size_t)t0 * SD);
    float4* gdst = (float4*)gs;
#pragma unroll
    for (int i = 0; i < 6; ++i) gdst[tid + i*256] = gsrc[tid + i*256];
    __syncthreads();

    bool act = v0 < VV;
    float2 acc[V_TT];
#pragma unroll
    for (int t = 0; t < V_TT; ++t) acc[t] = make_float2(0.f, 0.f);

    for (int k = 0; k < SD; k += 4) {
        float2 ve0, ve1, ve2, ve3;
        if (act) {
            ve0 = *(const float2*)(VE + (size_t)(k+0)*VV + v0);
            ve1 = *(const float2*)(VE + (size_t)(k+1)*VV + v0);
            ve2 = *(const float2*)(VE + (size_t)(k+2)*VV + v0);
            ve3 = *(const float2*)(VE + (size_t)(k+3)*VV + v0);
        } else {
            ve0 = ve1 = ve2 = ve3 = make_float2(0.f, 0.f);
        }
#pragma unroll
        for (int t = 0; t < V_TT; ++t) {
            float4 gv = *(const float4*)(&gs[t*SD + k]);
            acc[t].x += gv.x*ve0.x + gv.y*ve1.x + gv.z*ve2.x + gv.w*ve3.x;
            acc[t].y += gv.x*ve0.y + gv.y*ve1.y + gv.z*ve2.y + gv.w*ve3.y;
        }
    }
    if (act) {
#pragma unroll
        for (int t = 0; t < V_TT; ++t)
            *(float2*)(logits + (size_t)(t0+t)*VV + v0) = acc[t];
    }
}

// ===========================================================================
// root log-softmax (one wave)
// ===========================================================================
__global__ __launch_bounds__(64) void root_kernel(
    const float* __restrict__ root_emb, const float* __restrict__ rse,
    float* __restrict__ root_ls)
{
    int lane = threadIdx.x;
    float acc = 0.f;
    if (lane < NTC) {
        const float4* rr = (const float4*)(rse + (size_t)lane * SD);
        const float4* re = (const float4*)root_emb;
        for (int k = 0; k < SD/4; ++k) acc += dot4(re[k], rr[k]);
    }
    float mx = warp_max64(lane < NTC ? acc : -FINF);
    float ssum = warp_sum64(lane < NTC ? __expf(acc - mx) : 0.f);
    if (lane < NTC) root_ls[lane] = acc - (mx + __logf(ssum));
}

// ===========================================================================
// Column softmax (axis 0, 180 rules) of leftS/rightS, written INTERLEAVED:
//   clrG[p*128 + 2q + side] = softmax[p][q]        p<60   (left_m / right_m)
//   cprG[t*128 + 2q + side] = softmax[60+t][q]     t<120  (left_p / right_p)
// blockIdx.x = side (0 left, 1 right), lane = column q.
// ===========================================================================
__global__ __launch_bounds__(64) void softmax_rules(
    const float* __restrict__ leftS, const float* __restrict__ rightS,
    float* __restrict__ clrG, float* __restrict__ cprG)
{
    int side = blockIdx.x;
    const float* S = side ? rightS : leftS;
    int q = threadIdx.x;
    if (q >= NTC) return;
    float mx = -FINF;
    for (int r = 0; r < 180; ++r) mx = fmaxf(mx, S[r*NTC + q]);
    float ssum = 0.f;
    for (int r = 0; r < 180; ++r) ssum += __expf(S[r*NTC + q] - mx);
    float inv = 1.f / ssum;
    for (int r = 0; r < NTC; ++r)
        clrG[r*128 + 2*q + side] = __expf(S[r*NTC + q] - mx) * inv;
    for (int r = NTC; r < 180; ++r)
        cprG[(r-NTC)*128 + 2*q + side] = __expf(S[r*NTC + q] - mx) * inv;
}

// ===========================================================================
// lse over vocab rows
// ===========================================================================
__global__ __launch_bounds__(64) void lse_k(
    const float* __restrict__ logits, float* __restrict__ lse)
{
    int t = blockIdx.x, lane = threadIdx.x;
    const float4* row = (const float4*)(logits + (size_t)t * VV);
    float mx = -FINF, sm = 0.f;
    for (int i = lane; i < VV/4; i += 64) {
        float4 v = row[i];
        float m4 = fmaxf(fmaxf(v.x, v.y), fmaxf(v.z, v.w));
        float nm = fmaxf(mx, m4);
        sm = sm * __expf(mx - nm)
           + __expf(v.x-nm) + __expf(v.y-nm) + __expf(v.z-nm) + __expf(v.w-nm);
        mx = nm;
    }
#pragma unroll
    for (int off = 32; off > 0; off >>= 1) {
        float om = __shfl_xor(mx, off), os = __shfl_xor(sm, off);
        float nm = fmaxf(mx, om);
        sm = sm * __expf(mx - nm) + os * __expf(om - nm);
        mx = nm;
    }
    if (lane == 0) lse[t] = mx + __logf(sm);
}

// ===========================================================================
// init: LcB[b][1][n][p] = log(sum_t exp(unary)_t * left_p[t][p]) (+max), ditto R.
// unary[t] = logits[t, word[b,n]] - lse[t]. One wave per (b,n).
// ===========================================================================
__global__ __launch_bounds__(64) void init_k(
    const float* __restrict__ logits, const float* __restrict__ lse,
    const int* __restrict__ word, const float* __restrict__ cprG,
    float* __restrict__ LcB, float* __restrict__ RcB)
{
    int c = blockIdx.x;            // b*NN + n
    int b = c / NN, n = c % NN;
    int lane = threadIdx.x;
    __shared__ float sh[128];

    int wd = word[c];
    float u0 = logits[(size_t)lane * VV + wd] - lse[lane];
    int t1 = lane + 64;
    float u1 = (t1 < TTC) ? logits[(size_t)t1 * VV + wd] - lse[t1] : -FINF;
    float M = warp_max64(fmaxf(u0, u1));
    sh[lane]      = __expf(u0 - M);
    sh[lane + 64] = (t1 < TTC) ? __expf(u1 - M) : 0.f;
    __syncthreads();

    const float2* cp2 = (const float2*)cprG;
    float aL = 0.f, aR = 0.f;
#pragma unroll 4
    for (int t = 0; t < TTC; ++t) {
        float2 v = cp2[t*64 + lane];
        float e = sh[t];
        aL = fmaf(e, v.x, aL); aR = fmaf(e, v.y, aR);
    }
    if (lane < NTC) {
        size_t o = (size_t)b * TB + (NN + n) * NTC + lane;   // w = 1
        LcB[o] = __logf(aL) + M;
        RcB[o] = __logf(aR) + M;
    }
}

// ===========================================================================
// inside_b: the WHOLE 39-width CKY recursion for one batch element b.
// One block per b (128 blocks x 1024 threads = 16 waves). Widths separated by
// __syncthreads(); same-CU L1 is write-through so global RAW within the block
// is coherent. Each wave handles 2 cells per pass; logmm matrices in LDS
// interleaved float2 (conflict-free), e broadcast via shfl (VALU pipe).
// ===========================================================================
__global__ __launch_bounds__(1024) void inside_b(
    const float* __restrict__ clrG, const float* __restrict__ root_ls,
    float* LcB, float* RcB, float* __restrict__ out)
{
    __shared__ float2 clr2[NTC * 64];   // 30 KB: [p][q] {left_m, right_m}
    int b = blockIdx.x;
    int tid = threadIdx.x;
    int wave = tid >> 6, lane = tid & 63;

    const float2* cg2 = (const float2*)clrG;
    for (int i = tid; i < NTC * 64; i += 1024) clr2[i] = cg2[i];
    __syncthreads();

    float* Lb = LcB + (size_t)b * TB;
    float* Rb = RcB + (size_t)b * TB;
    int p = (lane < NTC) ? lane : (NTC - 1);

    for (int w = 2; w <= NN; ++w) {
        int m = NN - w + 1;
        for (int bi = wave; 2*bi < m; bi += 16) {
            int jA = 2*bi, jB = 2*bi + 1;
            bool hasB = (jB < m);
            int jBs = hasB ? jB : jA;

            const float* LA = Lb + (NN + jA)*NTC + p;
            const float* RA = Rb + ((w-1)*NN + jA + 1)*NTC + p;
            const float* LB = Lb + (NN + jBs)*NTC + p;
            const float* RB = Rb + ((w-1)*NN + jBs + 1)*NTC + p;
            const int DL = NN*NTC;          // +2400
            const int DR = (1-NN)*NTC;      // -2340

            float mxA = -FINF, smA = 0.f, mxB = -FINF, smB = 0.f;
            int k = 1;
            for (; k + 1 < w; k += 2) {
                float lA0 = LA[0], rA0 = RA[0];
                float lA1 = LA[DL], rA1 = RA[DR];
                float lB0 = LB[0], rB0 = RB[0];
                float lB1 = LB[DL], rB1 = RB[DR];
                LA += 2*DL; RA += 2*DR; LB += 2*DL; RB += 2*DR;
                float vA0 = lA0 + rA0, vA1 = lA1 + rA1;
                float nmA = fmaxf(mxA, fmaxf(vA0, vA1));
                smA = smA * __expf(mxA - nmA) + __expf(vA0 - nmA) + __expf(vA1 - nmA);
                mxA = nmA;
                float vB0 = lB0 + rB0, vB1 = lB1 + rB1;
                float nmB = fmaxf(mxB, fmaxf(vB0, vB1));
                smB = smB * __expf(mxB - nmB) + __expf(vB0 - nmB) + __expf(vB1 - nmB);
                mxB = nmB;
            }
            if (k < w) {
                float vA = LA[0] + RA[0];
                float nmA = fmaxf(mxA, vA);
                smA = smA * __expf(mxA - nmA) + __expf(vA - nmA);
                mxA = nmA;
                float vB = LB[0] + RB[0];
                float nmB = fmaxf(mxB, vB);
                smB = smB * __expf(mxB - nmB) + __expf(vB - nmB);
                mxB = nmB;
            }
            float betaA = __logf(smA) + mxA;

            if (w == NN) {   // single cell j=0: partition for this b
                float v = (lane < NTC) ? root_ls[lane] + betaA : -FINF;
                float mx = warp_max64(v);
                float s = warp_sum64(lane < NTC ? __expf(v - mx) : 0.f);
                if (lane == 0) out[b] = mx + __logf(s);
                continue;
            }
            float betaB = __logf(smB) + mxB;

            float bmA = warp_max64(betaA);
            float bmB = warp_max64(betaB);
            float eA = __expf(betaA - bmA);
            float eB = __expf(betaB - bmB);

            float aLA = 0.f, aRA = 0.f, aLB = 0.f, aRB = 0.f;
#pragma unroll 4
            for (int pp = 0; pp < NTC; ++pp) {
                float2 lr = clr2[pp*64 + lane];
                float ea = __shfl(eA, pp);
                float eb = __shfl(eB, pp);
                aLA = fmaf(ea, lr.x, aLA); aRA = fmaf(ea, lr.y, aRA);
                aLB = fmaf(eb, lr.x, aLB); aRB = fmaf(eb, lr.y, aRB);
            }
            if (lane < NTC) {
                int oA = (w*NN + jA)*NTC + lane;
                Lb[oA] = __logf(aLA) + bmA;
                Rb[oA] = __logf(aRA) + bmA;
                if (hasB) {
                    int oB = (w*NN + jB)*NTC + lane;
                    Lb[oB] = __logf(aLB) + bmB;
                    Rb[oB] = __logf(aRB) + bmB;
                }
            }
        }
        __syncthreads();
    }
}

// ===========================================================================
// loss = -mean(partition)
// ===========================================================================
__global__ __launch_bounds__(64) void mean_k(float* out)
{
    int lane = threadIdx.x;
    float s = out[lane] + out[lane + 64];
    s = warp_sum64(s);
    if (lane == 0) out[BB] = -s / (float)BB;
}

// ===========================================================================
extern "C" void kernel_launch(void* const* d_in, const int* in_sizes, int n_in,
                              void* d_out, int out_size, void* d_ws, size_t ws_size,
                              hipStream_t stream)
{
    const int*   word     = (const int*)  d_in[0];
    const float* root_emb = (const float*)d_in[1];
    const float* rse      = (const float*)d_in[2];   // (180, 512)
    const float* VE       = (const float*)d_in[3];   // (512, 10000)
    const float* W0       = (const float*)d_in[4];
    const float* b0       = (const float*)d_in[5];
    const float* W1       = (const float*)d_in[6];   // (3,512,512)
    const float* b1       = (const float*)d_in[7];
    const float* W2       = (const float*)d_in[8];
    const float* b2       = (const float*)d_in[9];
    const float* lW       = (const float*)d_in[10];
    const float* lb       = (const float*)d_in[11];
    const float* rW       = (const float*)d_in[12];
    const float* rb       = (const float*)d_in[13];
    const float* pW       = (const float*)d_in[14];
    const float* pb       = (const float*)d_in[15];

    float* ws = (float*)d_ws;
    size_t o = 0;
    float* logits  = ws + o; o += (size_t)TTC * VV;     // 1,200,000
    float* lse     = ws + o; o += 128;
    float* h       = ws + o; o += TTC * SD;
    float* u       = ws + o; o += TTC * SD;
    float* gbuf    = ws + o; o += TTC * SD;
    float* parent1 = ws + o; o += NTC * SD;
    float* leftH   = ws + o; o += 180 * SD;
    float* rightH  = ws + o; o += 180 * SD;
    float* leftS   = ws + o; o += 180 * NTC;
    float* rightS  = ws + o; o += 180 * NTC;
    float* clrG    = ws + o; o += NTC * 128;            // 7,680
    float* cprG    = ws + o; o += TTC * 128;            // 15,360
    float* root_ls = ws + o; o += 64;
    float* LcB     = ws + o; o += (size_t)BB * TB;      // 12,288,000
    float* RcB     = ws + o; o += (size_t)BB * TB;

    const float* term_emb = rse + NTC * SD;

    // ---- grammar: term MLP chain (serial, 120x512 each) ----
    gemm1<<<240, 256, 0, stream>>>(term_emb, W0, b0, nullptr, nullptr, h, TTC, SD, 0);
    for (int i = 0; i < 3; ++i) {
        gemm1<<<240, 256, 0, stream>>>(h, W1 + (size_t)i*SD*SD, b1 + i*SD,
                                       nullptr, nullptr, u, TTC, SD, 1);
        if (i < 2)
            gemm1<<<240, 256, 0, stream>>>(u, W2 + (size_t)i*SD*SD, b2 + i*SD,
                                           h, nullptr, h, TTC, SD, 1);
        else
            gemm1<<<240, 256, 0, stream>>>(u, W2 + (size_t)2*SD*SD, b2 + 2*SD,
                                           h, term_emb, gbuf, TTC, SD, 1);
    }
    // ---- vocab projection (depends on gbuf) ----
    vocab2<<<dim3(20, 10), 256, 0, stream>>>(gbuf, VE, logits);

    // ---- grammar: rules ----
    root_kernel<<<1, 64, 0, stream>>>(root_emb, rse, root_ls);
    gemm1<<<120, 256, 0, stream>>>(rse, pW, pb, rse, nullptr, parent1, NTC, SD, 1);
    gemm1<<<360, 256, 0, stream>>>(rse, lW, lb, rse, nullptr, leftH, 180, SD, 1);
    gemm1<<<360, 256, 0, stream>>>(rse, rW, rb, rse, nullptr, rightH, 180, SD, 1);
    gemm1<<<43, 256, 0, stream>>>(leftH,  parent1, nullptr, nullptr, nullptr, leftS,  180, NTC, 0);
    gemm1<<<43, 256, 0, stream>>>(rightH, parent1, nullptr, nullptr, nullptr, rightS, 180, NTC, 0);
    softmax_rules<<<2, 64, 0, stream>>>(leftS, rightS, clrG, cprG);

    // ---- inside algorithm ----
    lse_k<<<TTC, 64, 0, stream>>>(logits, lse);
    init_k<<<BB*NN, 64, 0, stream>>>(logits, lse, word, cprG, LcB, RcB);
    inside_b<<<BB, 1024, 0, stream>>>(clrG, root_ls, LcB, RcB, (float*)d_out);
    mean_k<<<1, 64, 0, stream>>>((float*)d_out);
}

// Round 13
// 736.964 us; speedup vs baseline: 13.2934x; 1.2627x over previous
//
#include <hip/hip_runtime.h>
#include <hip/hip_bf16.h>
#include <math.h>

#define NTC 60      // nonterminals
#define TTC 120     // preterminals
#define SD  512     // state dim
#define VV  10000   // vocab
#define BB  128     // batch
#define NN  40      // sentence length
#define TB  (NN*NN*NTC)     // 96000 floats per-b table [w][j][p]
#define SS  (SD*SD)
#define FINF __int_as_float(0x7f800000)

// ===========================================================================
__device__ inline float warp_max64(float v) {
#pragma unroll
    for (int off = 32; off > 0; off >>= 1) v = fmaxf(v, __shfl_xor(v, off));
    return v;
}
__device__ inline float warp_sum64(float v) {
#pragma unroll
    for (int off = 32; off > 0; off >>= 1) v += __shfl_xor(v, off);
    return v;
}
__device__ inline float dot4(float4 a, float4 b) {
    return a.x*b.x + a.y*b.y + a.z*b.z + a.w*b.w;
}
// dot of 512 floats: x (LDS, broadcast) . w (global row)
__device__ inline float dot512(const float* xs, const float* w) {
    const float4* w4 = (const float4*)w;
    const float4* x4 = (const float4*)xs;
    float a0 = 0.f, a1 = 0.f, a2 = 0.f, a3 = 0.f;
#pragma unroll 2
    for (int k = 0; k < SD/4; k += 4) {
        a0 += dot4(x4[k],   w4[k]);
        a1 += dot4(x4[k+1], w4[k+1]);
        a2 += dot4(x4[k+2], w4[k+2]);
        a3 += dot4(x4[k+3], w4[k+3]);
    }
    return (a0 + a1) + (a2 + a3);
}

// ===========================================================================
// grammar_A: blocks 0..119  -> full 7-layer term MLP for row t (no global
//                              intermediates; ping-pong LDS row buffers)
//            blocks 120..539 -> rules stage-1 rows:
//              120..179: parent1[r] = relu(rse[r]@pW.T+pb)+rse[r]
//              180..359: leftH[r]   = relu(rse[r]@lW.T+lb)+rse[r]
//              360..539: rightH[r]  = relu(rse[r]@rW.T+rb)+rse[r]
// 512 threads; thread = output column s.
// ===========================================================================
__global__ __launch_bounds__(512) void grammar_A(
    const float* __restrict__ rse,
    const float* __restrict__ W0, const float* __restrict__ b0,
    const float* __restrict__ W1, const float* __restrict__ b1,
    const float* __restrict__ W2, const float* __restrict__ b2,
    const float* __restrict__ lW, const float* __restrict__ lb,
    const float* __restrict__ rW, const float* __restrict__ rb,
    const float* __restrict__ pW, const float* __restrict__ pb,
    float* __restrict__ gbuf, float* __restrict__ parent1,
    float* __restrict__ leftH, float* __restrict__ rightH)
{
    __shared__ float xA[SD], xB[SD];
    int blk = blockIdx.x, s = threadIdx.x;

    if (blk < TTC) {
        // ---- term MLP for row t = blk ----
        const float* te = rse + (size_t)(NTC + blk) * SD;
        float tev = te[s];
        xA[s] = tev;
        __syncthreads();
        float h = dot512(xA, W0 + (size_t)s * SD) + b0[s];
        xB[s] = h;
        __syncthreads();
        for (int i = 0; i < 3; ++i) {
            float u = fmaxf(dot512(xB, W1 + (size_t)i*SS + (size_t)s*SD) + b1[i*SD + s], 0.f);
            __syncthreads();
            xA[s] = u;
            __syncthreads();
            float r = fmaxf(dot512(xA, W2 + (size_t)i*SS + (size_t)s*SD) + b2[i*SD + s], 0.f);
            h = r + h;
            __syncthreads();
            xB[s] = h;
            __syncthreads();
        }
        gbuf[(size_t)blk * SD + s] = h + tev;
    } else {
        int q = blk - TTC;
        const float* W; const float* bia; float* dst; int row;
        if (q < NTC)       { W = pW; bia = pb; dst = parent1; row = q; }
        else if (q < 240)  { W = lW; bia = lb; dst = leftH;   row = q - 60; }
        else               { W = rW; bia = rb; dst = rightH;  row = q - 240; }
        const float* x = rse + (size_t)row * SD;
        xA[s] = x[s];
        __syncthreads();
        float v = fmaxf(dot512(xA, W + (size_t)s * SD) + bia[s], 0.f) + xA[s];
        dst[(size_t)row * SD + s] = v;
    }
}

// ===========================================================================
// grammar_B: leftS/rightS = {left,right}H' @ parent1.T  (2 x 180 x 60 outputs)
// ===========================================================================
__global__ __launch_bounds__(256) void grammar_B(
    const float* __restrict__ leftH, const float* __restrict__ rightH,
    const float* __restrict__ parent1,
    float* __restrict__ leftS, float* __restrict__ rightS)
{
    int o = blockIdx.x * 256 + threadIdx.x;
    if (o >= 2 * 180 * NTC) return;
    int side = o / (180 * NTC), rem = o % (180 * NTC);
    int r = rem / NTC, q = rem % NTC;
    const float* hh = (side ? rightH : leftH) + (size_t)r * SD;
    const float* pp = parent1 + (size_t)q * SD;
    const float4* h4 = (const float4*)hh;
    const float4* p4 = (const float4*)pp;
    float a0=0.f,a1=0.f,a2=0.f,a3=0.f;
#pragma unroll 2
    for (int k = 0; k < SD/4; k += 4) {
        a0 += dot4(h4[k],   p4[k]);
        a1 += dot4(h4[k+1], p4[k+1]);
        a2 += dot4(h4[k+2], p4[k+2]);
        a3 += dot4(h4[k+3], p4[k+3]);
    }
    (side ? rightS : leftS)[r * NTC + q] = (a0 + a1) + (a2 + a3);
}

// ===========================================================================
// grammar_C: blocks 0,1 = column softmax of leftS/rightS -> interleaved
//   clrG[p*128 + 2q + side] (p<60), cprG[t*128 + 2q + side] (t<120)
// block 2 = root log-softmax.
// ===========================================================================
__global__ __launch_bounds__(64) void grammar_C(
    const float* __restrict__ leftS, const float* __restrict__ rightS,
    const float* __restrict__ root_emb, const float* __restrict__ rse,
    float* __restrict__ clrG, float* __restrict__ cprG,
    float* __restrict__ root_ls)
{
    int lane = threadIdx.x;
    if (blockIdx.x < 2) {
        int side = blockIdx.x;
        const float* S = side ? rightS : leftS;
        int q = lane;
        if (q >= NTC) return;
        float mx = -FINF;
        for (int r = 0; r < 180; ++r) mx = fmaxf(mx, S[r*NTC + q]);
        float ssum = 0.f;
        for (int r = 0; r < 180; ++r) ssum += __expf(S[r*NTC + q] - mx);
        float inv = 1.f / ssum;
        for (int r = 0; r < NTC; ++r)
            clrG[r*128 + 2*q + side] = __expf(S[r*NTC + q] - mx) * inv;
        for (int r = NTC; r < 180; ++r)
            cprG[(r-NTC)*128 + 2*q + side] = __expf(S[r*NTC + q] - mx) * inv;
    } else {
        float acc = 0.f;
        if (lane < NTC) {
            const float4* rr = (const float4*)(rse + (size_t)lane * SD);
            const float4* re = (const float4*)root_emb;
            for (int k = 0; k < SD/4; ++k) acc += dot4(re[k], rr[k]);
        }
        float mx = warp_max64(lane < NTC ? acc : -FINF);
        float ssum = warp_sum64(lane < NTC ? __expf(acc - mx) : 0.f);
        if (lane < NTC) root_ls[lane] = acc - (mx + __logf(ssum));
    }
}

// ===========================================================================
// vocab2: logits[t,v] = sum_k g[t,k]*VE[k,v].  grid (20, 10), block 256.
// ===========================================================================
#define V_TT 12
__global__ __launch_bounds__(256) void vocab2(
    const float* __restrict__ g, const float* __restrict__ VE,
    float* __restrict__ logits)
{
    __shared__ float gs[V_TT * SD];
    int tid = threadIdx.x;
    int t0 = blockIdx.y * V_TT;
    int v0 = blockIdx.x * 512 + tid * 2;

    const float4* gsrc = (const float4*)(g + (size_t)t0 * SD);
    float4* gdst = (float4*)gs;
#pragma unroll
    for (int i = 0; i < 6; ++i) gdst[tid + i*256] = gsrc[tid + i*256];
    __syncthreads();

    bool act = v0 < VV;
    float2 acc[V_TT];
#pragma unroll
    for (int t = 0; t < V_TT; ++t) acc[t] = make_float2(0.f, 0.f);

    for (int k = 0; k < SD; k += 4) {
        float2 ve0, ve1, ve2, ve3;
        if (act) {
            ve0 = *(const float2*)(VE + (size_t)(k+0)*VV + v0);
            ve1 = *(const float2*)(VE + (size_t)(k+1)*VV + v0);
            ve2 = *(const float2*)(VE + (size_t)(k+2)*VV + v0);
            ve3 = *(const float2*)(VE + (size_t)(k+3)*VV + v0);
        } else {
            ve0 = ve1 = ve2 = ve3 = make_float2(0.f, 0.f);
        }
#pragma unroll
        for (int t = 0; t < V_TT; ++t) {
            float4 gv = *(const float4*)(&gs[t*SD + k]);
            acc[t].x += gv.x*ve0.x + gv.y*ve1.x + gv.z*ve2.x + gv.w*ve3.x;
            acc[t].y += gv.x*ve0.y + gv.y*ve1.y + gv.z*ve2.y + gv.w*ve3.y;
        }
    }
    if (act) {
#pragma unroll
        for (int t = 0; t < V_TT; ++t)
            *(float2*)(logits + (size_t)(t0+t)*VV + v0) = acc[t];
    }
}

// ===========================================================================
// lse over vocab rows (256 threads per row)
// ===========================================================================
__global__ __launch_bounds__(256) void lse_k(
    const float* __restrict__ logits, float* __restrict__ lse)
{
    int t = blockIdx.x, tid = threadIdx.x;
    int wave = tid >> 6, lane = tid & 63;
    const float4* row = (const float4*)(logits + (size_t)t * VV);
    float mx = -FINF, sm = 0.f;
    for (int i = tid; i < VV/4; i += 256) {
        float4 v = row[i];
        float m4 = fmaxf(fmaxf(v.x, v.y), fmaxf(v.z, v.w));
        float nm = fmaxf(mx, m4);
        sm = sm * __expf(mx - nm)
           + __expf(v.x-nm) + __expf(v.y-nm) + __expf(v.z-nm) + __expf(v.w-nm);
        mx = nm;
    }
#pragma unroll
    for (int off = 32; off > 0; off >>= 1) {
        float om = __shfl_xor(mx, off), os = __shfl_xor(sm, off);
        float nm = fmaxf(mx, om);
        sm = sm * __expf(mx - nm) + os * __expf(om - nm);
        mx = nm;
    }
    __shared__ float2 red[4];
    if (lane == 0) red[wave] = make_float2(mx, sm);
    __syncthreads();
    if (tid == 0) {
        float M = red[0].x, S = red[0].y;
        for (int i = 1; i < 4; ++i) {
            float nm = fmaxf(M, red[i].x);
            S = S * __expf(M - nm) + red[i].y * __expf(red[i].x - nm);
            M = nm;
        }
        lse[t] = M + __logf(S);
    }
}

// ===========================================================================
// online logsumexp over a strided (L,R) pair walk, unroll 4.
// ===========================================================================
__device__ inline void onlsum(const float* pL, const float* pR,
                              int dl, int dr, int kcount,
                              float& mx, float& sm)
{
    mx = -FINF; sm = 0.f;
    int i = 0;
    for (; i + 4 <= kcount; i += 4) {
        float l0 = pL[0],    r0 = pR[0];
        float l1 = pL[dl],   r1 = pR[dr];
        float l2 = pL[2*dl], r2 = pR[2*dr];
        float l3 = pL[3*dl], r3 = pR[3*dr];
        pL += 4*dl; pR += 4*dr;
        float v0 = l0+r0, v1 = l1+r1, v2 = l2+r2, v3 = l3+r3;
        float nm = fmaxf(fmaxf(fmaxf(v0,v1), fmaxf(v2,v3)), mx);
        sm = sm * __expf(mx - nm)
           + __expf(v0-nm) + __expf(v1-nm) + __expf(v2-nm) + __expf(v3-nm);
        mx = nm;
    }
    for (; i < kcount; ++i) {
        float v = pL[0] + pR[0];
        pL += dl; pR += dr;
        float nm = fmaxf(mx, v);
        sm = sm * __expf(mx - nm) + __expf(v - nm);
        mx = nm;
    }
}

// ===========================================================================
// inside_b: init (w=1) + whole CKY recursion + partition for one b.
// 128 blocks x 1024 threads (16 waves).
//  m>=17 : stride-16 cell pairing (2-cell ILP, balanced)
//  9<=m<=16: one wave per cell, unroll-4 k-loop
//  m<=8  : G=16/m waves k-split per cell, LDS partial combine
// matvec e-broadcast via LDS float4 reads (no shfl).
// ===========================================================================
__global__ __launch_bounds__(1024) void inside_b(
    const float* __restrict__ logits, const float* __restrict__ lse,
    const int* __restrict__ word,
    const float* __restrict__ clrG, const float* __restrict__ cprG,
    const float* __restrict__ root_ls,
    float* LcB, float* RcB, float* __restrict__ out)
{
    __shared__ float2 clr2[NTC * 64];   // 30 KB [p][q]{left_m,right_m}
    __shared__ float2 part[16 * 64];    // 8 KB partial (mx,sm)
    __shared__ float  esh[16 * 128];    // 8 KB per-wave e buffers

    int b = blockIdx.x;
    int tid = threadIdx.x;
    int wave = tid >> 6, lane = tid & 63;

    const float2* cg2 = (const float2*)clrG;
    for (int i = tid; i < NTC * 64; i += 1024) clr2[i] = cg2[i];

    float* Lb = LcB + (size_t)b * TB;
    float* Rb = RcB + (size_t)b * TB;
    int p = (lane < NTC) ? lane : (NTC - 1);
    const int DL = NN * NTC;        // +2400
    const int DR = (1 - NN) * NTC;  // -2340

    // ---- w = 1 init (fused old init_k) ----
    const float2* cp2 = (const float2*)cprG;
    for (int n = wave; n < NN; n += 16) {
        int wd = word[b * NN + n];
        float u0 = logits[(size_t)lane * VV + wd] - lse[lane];
        float u1 = (lane < TTC - 64) ? logits[(size_t)(lane + 64) * VV + wd] - lse[lane + 64]
                                     : -FINF;
        float M = warp_max64(fmaxf(u0, u1));
        float* e = esh + wave * 128;
        e[lane]      = __expf(u0 - M);
        e[lane + 64] = (lane < TTC - 64) ? __expf(u1 - M) : 0.f;
        const float4* e4 = (const float4*)e;
        float aL = 0.f, aR = 0.f;
#pragma unroll 5
        for (int i = 0; i < 30; ++i) {
            float4 ev = e4[i];
            float2 c0 = cp2[(4*i+0)*64 + p];
            float2 c1 = cp2[(4*i+1)*64 + p];
            float2 c2 = cp2[(4*i+2)*64 + p];
            float2 c3 = cp2[(4*i+3)*64 + p];
            aL = fmaf(ev.x, c0.x, aL); aR = fmaf(ev.x, c0.y, aR);
            aL = fmaf(ev.y, c1.x, aL); aR = fmaf(ev.y, c1.y, aR);
            aL = fmaf(ev.z, c2.x, aL); aR = fmaf(ev.z, c2.y, aR);
            aL = fmaf(ev.w, c3.x, aL); aR = fmaf(ev.w, c3.y, aR);
        }
        if (lane < NTC) {
            int o = (NN + n) * NTC + lane;
            Lb[o] = __logf(aL) + M;
            Rb[o] = __logf(aR) + M;
        }
    }
    __syncthreads();

    // ---- widths 2..40 ----
    for (int w = 2; w <= NN; ++w) {
        int m = NN - w + 1;
        if (m >= 17) {
            // paired cells: cA = c0, cB = c0 + 16
            for (int c0 = wave; c0 < m; c0 += 32) {
                int jA = c0, jB = c0 + 16;
                bool hasB = (jB < m);
                int jBs = hasB ? jB : jA;
                const float* LA = Lb + (NN + jA)*NTC + p;
                const float* RA = Rb + ((w-1)*NN + jA + 1)*NTC + p;
                const float* LB = Lb + (NN + jBs)*NTC + p;
                const float* RB = Rb + ((w-1)*NN + jBs + 1)*NTC + p;

                float mxA = -FINF, smA = 0.f, mxB = -FINF, smB = 0.f;
                int k = 1;
                for (; k + 1 < w; k += 2) {
                    float lA0 = LA[0],  rA0 = RA[0];
                    float lA1 = LA[DL], rA1 = RA[DR];
                    float lB0 = LB[0],  rB0 = RB[0];
                    float lB1 = LB[DL], rB1 = RB[DR];
                    LA += 2*DL; RA += 2*DR; LB += 2*DL; RB += 2*DR;
                    float vA0 = lA0+rA0, vA1 = lA1+rA1;
                    float nmA = fmaxf(mxA, fmaxf(vA0, vA1));
                    smA = smA * __expf(mxA-nmA) + __expf(vA0-nmA) + __expf(vA1-nmA);
                    mxA = nmA;
                    float vB0 = lB0+rB0, vB1 = lB1+rB1;
                    float nmB = fmaxf(mxB, fmaxf(vB0, vB1));
                    smB = smB * __expf(mxB-nmB) + __expf(vB0-nmB) + __expf(vB1-nmB);
                    mxB = nmB;
                }
                if (k < w) {
                    float vA = LA[0] + RA[0];
                    float nmA = fmaxf(mxA, vA);
                    smA = smA * __expf(mxA-nmA) + __expf(vA-nmA);
                    mxA = nmA;
                    float vB = LB[0] + RB[0];
                    float nmB = fmaxf(mxB, vB);
                    smB = smB * __expf(mxB-nmB) + __expf(vB-nmB);
                    mxB = nmB;
                }
                float betaA = __logf(smA) + mxA;
                float betaB = __logf(smB) + mxB;

                float bmA = warp_max64(betaA);
                float bmB = warp_max64(betaB);
                float* eA = esh + wave * 128;
                float* eB = eA + 64;
                eA[lane] = (lane < NTC) ? __expf(betaA - bmA) : 0.f;
                eB[lane] = (lane < NTC && hasB) ? __expf(betaB - bmB) : 0.f;
                const float4* eA4 = (const float4*)eA;
                const float4* eB4 = (const float4*)eB;
                float aLA=0.f, aRA=0.f, aLB=0.f, aRB=0.f;
#pragma unroll 5
                for (int i = 0; i < 15; ++i) {
                    float4 ea = eA4[i], eb = eB4[i];
                    float2 l0 = clr2[(4*i+0)*64 + lane];
                    float2 l1 = clr2[(4*i+1)*64 + lane];
                    float2 l2 = clr2[(4*i+2)*64 + lane];
                    float2 l3 = clr2[(4*i+3)*64 + lane];
                    aLA = fmaf(ea.x, l0.x, aLA); aRA = fmaf(ea.x, l0.y, aRA);
                    aLB = fmaf(eb.x, l0.x, aLB); aRB = fmaf(eb.x, l0.y, aRB);
                    aLA = fmaf(ea.y, l1.x, aLA); aRA = fmaf(ea.y, l1.y, aRA);
                    aLB = fmaf(eb.y, l1.x, aLB); aRB = fmaf(eb.y, l1.y, aRB);
                    aLA = fmaf(ea.z, l2.x, aLA); aRA = fmaf(ea.z, l2.y, aRA);
                    aLB = fmaf(eb.z, l2.x, aLB); aRB = fmaf(eb.z, l2.y, aRB);
                    aLA = fmaf(ea.w, l3.x, aLA); aRA = fmaf(ea.w, l3.y, aRA);
                    aLB = fmaf(eb.w, l3.x, aLB); aRB = fmaf(eb.w, l3.y, aRB);
                }
                if (lane < NTC) {
                    int oA = (w*NN + jA)*NTC + lane;
                    Lb[oA] = __logf(aLA) + bmA;
                    Rb[oA] = __logf(aRA) + bmA;
                    if (hasB) {
                        int oB = (w*NN + jB)*NTC + lane;
                        Lb[oB] = __logf(aLB) + bmB;
                        Rb[oB] = __logf(aRB) + bmB;
                    }
                }
            }
        } else if (m >= 9) {
            // one wave per cell
            if (wave < m) {
                int j = wave;
                const float* pL = Lb + (NN + j)*NTC + p;
                const float* pR = Rb + ((w-1)*NN + j + 1)*NTC + p;
                float mx, sm;
                onlsum(pL, pR, DL, DR, w - 1, mx, sm);
                float beta = __logf(sm) + mx;
                float bm = warp_max64(beta);
                float* e = esh + wave * 128;
                e[lane] = (lane < NTC) ? __expf(beta - bm) : 0.f;
                const float4* e4 = (const float4*)e;
                float aL = 0.f, aR = 0.f;
#pragma unroll 5
                for (int i = 0; i < 15; ++i) {
                    float4 ev = e4[i];
                    float2 l0 = clr2[(4*i+0)*64 + lane];
                    float2 l1 = clr2[(4*i+1)*64 + lane];
                    float2 l2 = clr2[(4*i+2)*64 + lane];
                    float2 l3 = clr2[(4*i+3)*64 + lane];
                    aL = fmaf(ev.x, l0.x, aL); aR = fmaf(ev.x, l0.y, aR);
                    aL = fmaf(ev.y, l1.x, aL); aR = fmaf(ev.y, l1.y, aR);
                    aL = fmaf(ev.z, l2.x, aL); aR = fmaf(ev.z, l2.y, aR);
                    aL = fmaf(ev.w, l3.x, aL); aR = fmaf(ev.w, l3.y, aR);
                }
                if (lane < NTC) {
                    int o = (w*NN + j)*NTC + lane;
                    Lb[o] = __logf(aL) + bm;
                    Rb[o] = __logf(aR) + bm;
                }
            }
        } else {
            // k-split: G = 16/m waves per cell
            int G = 16 / m;
            if (wave < G * m) {
                int c = wave % m, g = wave / m;
                int k0 = 1 + g;
                const float* pL = Lb + (k0*NN + c)*NTC + p;
                const float* pR = Rb + ((w-k0)*NN + c + k0)*NTC + p;
                int kcount = (w - k0 + G - 1) / G;
                float mx, sm;
                onlsum(pL, pR, G*DL, G*DR, kcount, mx, sm);
                part[tid >> 6 << 6 | lane] = make_float2(mx, sm); // part[wave*64+lane]
            }
            __syncthreads();
            if (wave < m) {
                int c = wave;
                float mx = -FINF, sm = 0.f;
                for (int g = 0; g < G; ++g) {
                    float2 pr = part[(g*m + c)*64 + lane];
                    float nm = fmaxf(mx, pr.x);
                    sm = sm * __expf(mx - nm) + pr.y * __expf(pr.x - nm);
                    mx = nm;
                }
                float beta = __logf(sm) + mx;
                if (w == NN) {
                    float v = (lane < NTC) ? root_ls[lane] + beta : -FINF;
                    float vm = warp_max64(v);
                    float vs = warp_sum64(lane < NTC ? __expf(v - vm) : 0.f);
                    if (lane == 0) out[b] = vm + __logf(vs);
                } else {
                    float bm = warp_max64(beta);
                    float* e = esh + wave * 128;
                    e[lane] = (lane < NTC) ? __expf(beta - bm) : 0.f;
                    const float4* e4 = (const float4*)e;
                    float aL = 0.f, aR = 0.f;
#pragma unroll 5
                    for (int i = 0; i < 15; ++i) {
                        float4 ev = e4[i];
                        float2 l0 = clr2[(4*i+0)*64 + lane];
                        float2 l1 = clr2[(4*i+1)*64 + lane];
                        float2 l2 = clr2[(4*i+2)*64 + lane];
                        float2 l3 = clr2[(4*i+3)*64 + lane];
                        aL = fmaf(ev.x, l0.x, aL); aR = fmaf(ev.x, l0.y, aR);
                        aL = fmaf(ev.y, l1.x, aL); aR = fmaf(ev.y, l1.y, aR);
                        aL = fmaf(ev.z, l2.x, aL); aR = fmaf(ev.z, l2.y, aR);
                        aL = fmaf(ev.w, l3.x, aL); aR = fmaf(ev.w, l3.y, aR);
                    }
                    if (lane < NTC) {
                        int o = (w*NN + c)*NTC + lane;
                        Lb[o] = __logf(aL) + bm;
                        Rb[o] = __logf(aR) + bm;
                    }
                }
            }
        }
        __syncthreads();
    }
}

// ===========================================================================
// loss = -mean(partition)
// ===========================================================================
__global__ __launch_bounds__(64) void mean_k(float* out)
{
    int lane = threadIdx.x;
    float s = out[lane] + out[lane + 64];
    s = warp_sum64(s);
    if (lane == 0) out[BB] = -s / (float)BB;
}

// ===========================================================================
extern "C" void kernel_launch(void* const* d_in, const int* in_sizes, int n_in,
                              void* d_out, int out_size, void* d_ws, size_t ws_size,
                              hipStream_t stream)
{
    const int*   word     = (const int*)  d_in[0];
    const float* root_emb = (const float*)d_in[1];
    const float* rse      = (const float*)d_in[2];   // (180, 512)
    const float* VE       = (const float*)d_in[3];   // (512, 10000)
    const float* W0       = (const float*)d_in[4];
    const float* b0       = (const float*)d_in[5];
    const float* W1       = (const float*)d_in[6];   // (3,512,512)
    const float* b1       = (const float*)d_in[7];
    const float* W2       = (const float*)d_in[8];
    const float* b2       = (const float*)d_in[9];
    const float* lW       = (const float*)d_in[10];
    const float* lb       = (const float*)d_in[11];
    const float* rW       = (const float*)d_in[12];
    const float* rb       = (const float*)d_in[13];
    const float* pW       = (const float*)d_in[14];
    const float* pb       = (const float*)d_in[15];

    float* ws = (float*)d_ws;
    size_t o = 0;
    float* logits  = ws + o; o += (size_t)TTC * VV;     // 1,200,000
    float* lse     = ws + o; o += 128;
    float* gbuf    = ws + o; o += TTC * SD;
    float* parent1 = ws + o; o += NTC * SD;
    float* leftH   = ws + o; o += 180 * SD;
    float* rightH  = ws + o; o += 180 * SD;
    float* leftS   = ws + o; o += 180 * NTC;
    float* rightS  = ws + o; o += 180 * NTC;
    float* clrG    = ws + o; o += NTC * 128;
    float* cprG    = ws + o; o += TTC * 128;
    float* root_ls = ws + o; o += 64;
    float* LcB     = ws + o; o += (size_t)BB * TB;      // 12,288,000
    float* RcB     = ws + o; o += (size_t)BB * TB;

    grammar_A<<<540, 512, 0, stream>>>(rse, W0, b0, W1, b1, W2, b2,
                                       lW, lb, rW, rb, pW, pb,
                                       gbuf, parent1, leftH, rightH);
    grammar_B<<<85, 256, 0, stream>>>(leftH, rightH, parent1, leftS, rightS);
    grammar_C<<<3, 64, 0, stream>>>(leftS, rightS, root_emb, rse,
                                    clrG, cprG, root_ls);
    vocab2<<<dim3(20, 10), 256, 0, stream>>>(gbuf, VE, logits);
    lse_k<<<TTC, 256, 0, stream>>>(logits, lse);
    inside_b<<<BB, 1024, 0, stream>>>(logits, lse, word, clrG, cprG, root_ls,
                                      LcB, RcB, (float*)d_out);
    mean_k<<<1, 64, 0, stream>>>((float*)d_out);
}

// Round 14
// 717.307 us; speedup vs baseline: 13.6577x; 1.0274x over previous
//
#include <hip/hip_runtime.h>
#include <hip/hip_bf16.h>
#include <math.h>

#define NTC 60      // nonterminals
#define TTC 120     // preterminals
#define SD  512     // state dim
#define VV  10000   // vocab
#define BB  128     // batch
#define NN  40      // sentence length
#define TB  (NN*NN*NTC)     // 96000 floats per-b table [w][j][p]
#define SS  (SD*SD)
#define FINF __int_as_float(0x7f800000)

// Force-1-block-per-CU pad: block LDS must exceed 163840/2 = 81920 B.
// Pad is written+asm-consumed so the compiler cannot eliminate it (rule #17).
#define KEEP_PAD(padarr) do { \
    padarr[threadIdx.x] = 0.f; \
    asm volatile("" :: "v"(padarr[threadIdx.x])); } while (0)

// ===========================================================================
__device__ inline float warp_max64(float v) {
#pragma unroll
    for (int off = 32; off > 0; off >>= 1) v = fmaxf(v, __shfl_xor(v, off));
    return v;
}
__device__ inline float warp_sum64(float v) {
#pragma unroll
    for (int off = 32; off > 0; off >>= 1) v += __shfl_xor(v, off);
    return v;
}
__device__ inline float dot4(float4 a, float4 b) {
    return a.x*b.x + a.y*b.y + a.z*b.z + a.w*b.w;
}
__device__ inline float dot512(const float* xs, const float* w) {
    const float4* w4 = (const float4*)w;
    const float4* x4 = (const float4*)xs;
    float a0 = 0.f, a1 = 0.f, a2 = 0.f, a3 = 0.f;
#pragma unroll 2
    for (int k = 0; k < SD/4; k += 4) {
        a0 += dot4(x4[k],   w4[k]);
        a1 += dot4(x4[k+1], w4[k+1]);
        a2 += dot4(x4[k+2], w4[k+2]);
        a3 += dot4(x4[k+3], w4[k+3]);
    }
    return (a0 + a1) + (a2 + a3);
}

// ===========================================================================
// grammar_A: blocks 0..119 -> 7-layer term MLP row t; 120..539 rules stage-1.
// LDS-padded to 86 KB -> 1 block/CU (MLP chains get dedicated CUs).
// ===========================================================================
__global__ __launch_bounds__(512) void grammar_A(
    const float* __restrict__ rse,
    const float* __restrict__ W0, const float* __restrict__ b0,
    const float* __restrict__ W1, const float* __restrict__ b1,
    const float* __restrict__ W2, const float* __restrict__ b2,
    const float* __restrict__ lW, const float* __restrict__ lb,
    const float* __restrict__ rW, const float* __restrict__ rb,
    const float* __restrict__ pW, const float* __restrict__ pb,
    float* __restrict__ gbuf, float* __restrict__ parent1,
    float* __restrict__ leftH, float* __restrict__ rightH)
{
    __shared__ float xA[SD], xB[SD];
    __shared__ float lds_pad[20480];   // 80 KB pad -> total 86016 B
    KEEP_PAD(lds_pad);
    int blk = blockIdx.x, s = threadIdx.x;

    if (blk < TTC) {
        const float* te = rse + (size_t)(NTC + blk) * SD;
        float tev = te[s];
        xA[s] = tev;
        __syncthreads();
        float h = dot512(xA, W0 + (size_t)s * SD) + b0[s];
        xB[s] = h;
        __syncthreads();
        for (int i = 0; i < 3; ++i) {
            float u = fmaxf(dot512(xB, W1 + (size_t)i*SS + (size_t)s*SD) + b1[i*SD + s], 0.f);
            __syncthreads();
            xA[s] = u;
            __syncthreads();
            float r = fmaxf(dot512(xA, W2 + (size_t)i*SS + (size_t)s*SD) + b2[i*SD + s], 0.f);
            h = r + h;
            __syncthreads();
            xB[s] = h;
            __syncthreads();
        }
        gbuf[(size_t)blk * SD + s] = h + tev;
    } else {
        int q = blk - TTC;
        const float* W; const float* bia; float* dst; int row;
        if (q < NTC)       { W = pW; bia = pb; dst = parent1; row = q; }
        else if (q < 240)  { W = lW; bia = lb; dst = leftH;   row = q - 60; }
        else               { W = rW; bia = rb; dst = rightH;  row = q - 240; }
        const float* x = rse + (size_t)row * SD;
        xA[s] = x[s];
        __syncthreads();
        float v = fmaxf(dot512(xA, W + (size_t)s * SD) + bia[s], 0.f) + xA[s];
        dst[(size_t)row * SD + s] = v;
    }
}

// ===========================================================================
// vb_k: blocks 0..199 = vocab2 tile (vt=blk%20, tt=blk/20);
//       blocks 200..284 = grammar_B outputs (leftS/rightS).
// LDS-padded to 86 KB -> 1 block/CU.
// ===========================================================================
#define V_TT 12
__global__ __launch_bounds__(256) void vb_k(
    const float* __restrict__ g, const float* __restrict__ VE,
    float* __restrict__ logits,
    const float* __restrict__ leftH, const float* __restrict__ rightH,
    const float* __restrict__ parent1,
    float* __restrict__ leftS, float* __restrict__ rightS)
{
    __shared__ float gs[V_TT * SD];     // 24576 B
    __shared__ float lds_pad[15360];    // 61440 B -> total 86016 B
    KEEP_PAD(lds_pad);
    int blk = blockIdx.x, tid = threadIdx.x;

    if (blk < 200) {
        int t0 = (blk / 20) * V_TT;
        int v0 = (blk % 20) * 512 + tid * 2;

        const float4* gsrc = (const float4*)(g + (size_t)t0 * SD);
        float4* gdst = (float4*)gs;
#pragma unroll
        for (int i = 0; i < 6; ++i) gdst[tid + i*256] = gsrc[tid + i*256];
        __syncthreads();

        bool act = v0 < VV;
        float2 acc[V_TT];
#pragma unroll
        for (int t = 0; t < V_TT; ++t) acc[t] = make_float2(0.f, 0.f);

        for (int k = 0; k < SD; k += 4) {
            float2 ve0, ve1, ve2, ve3;
            if (act) {
                ve0 = *(const float2*)(VE + (size_t)(k+0)*VV + v0);
                ve1 = *(const float2*)(VE + (size_t)(k+1)*VV + v0);
                ve2 = *(const float2*)(VE + (size_t)(k+2)*VV + v0);
                ve3 = *(const float2*)(VE + (size_t)(k+3)*VV + v0);
            } else {
                ve0 = ve1 = ve2 = ve3 = make_float2(0.f, 0.f);
            }
#pragma unroll
            for (int t = 0; t < V_TT; ++t) {
                float4 gv = *(const float4*)(&gs[t*SD + k]);
                acc[t].x += gv.x*ve0.x + gv.y*ve1.x + gv.z*ve2.x + gv.w*ve3.x;
                acc[t].y += gv.x*ve0.y + gv.y*ve1.y + gv.z*ve2.y + gv.w*ve3.y;
            }
        }
        if (act) {
#pragma unroll
            for (int t = 0; t < V_TT; ++t)
                *(float2*)(logits + (size_t)(t0+t)*VV + v0) = acc[t];
        }
    } else {
        int o = (blk - 200) * 256 + tid;
        if (o >= 2 * 180 * NTC) return;
        int side = o / (180 * NTC), rem = o % (180 * NTC);
        int r = rem / NTC, q = rem % NTC;
        const float* hh = (side ? rightH : leftH) + (size_t)r * SD;
        const float* pp = parent1 + (size_t)q * SD;
        const float4* h4 = (const float4*)hh;
        const float4* p4 = (const float4*)pp;
        float a0=0.f,a1=0.f,a2=0.f,a3=0.f;
#pragma unroll 2
        for (int k = 0; k < SD/4; k += 4) {
            a0 += dot4(h4[k],   p4[k]);
            a1 += dot4(h4[k+1], p4[k+1]);
            a2 += dot4(h4[k+2], p4[k+2]);
            a3 += dot4(h4[k+3], p4[k+3]);
        }
        (side ? rightS : leftS)[r * NTC + q] = (a0 + a1) + (a2 + a3);
    }
}

// ===========================================================================
// lc_k: blocks 0..119 = lse over logits row t=blk (256 threads);
//       blocks 120,121 = column softmax of leftS/rightS -> clrG/cprG;
//       block 122 = root log-softmax.
// LDS-padded -> 1 block/CU.
// ===========================================================================
__global__ __launch_bounds__(256) void lc_k(
    const float* __restrict__ logits, float* __restrict__ lse,
    const float* __restrict__ leftS, const float* __restrict__ rightS,
    const float* __restrict__ root_emb, const float* __restrict__ rse,
    float* __restrict__ clrG, float* __restrict__ cprG,
    float* __restrict__ root_ls)
{
    __shared__ float2 red[4];
    __shared__ float lds_pad[21504];    // 86016 B pad
    KEEP_PAD(lds_pad);
    int blk = blockIdx.x, tid = threadIdx.x;
    int wave = tid >> 6, lane = tid & 63;

    if (blk < TTC) {
        int t = blk;
        const float4* row = (const float4*)(logits + (size_t)t * VV);
        float mx = -FINF, sm = 0.f;
        for (int i = tid; i < VV/4; i += 256) {
            float4 v = row[i];
            float m4 = fmaxf(fmaxf(v.x, v.y), fmaxf(v.z, v.w));
            float nm = fmaxf(mx, m4);
            sm = sm * __expf(mx - nm)
               + __expf(v.x-nm) + __expf(v.y-nm) + __expf(v.z-nm) + __expf(v.w-nm);
            mx = nm;
        }
#pragma unroll
        for (int off = 32; off > 0; off >>= 1) {
            float om = __shfl_xor(mx, off), os = __shfl_xor(sm, off);
            float nm = fmaxf(mx, om);
            sm = sm * __expf(mx - nm) + os * __expf(om - nm);
            mx = nm;
        }
        if (lane == 0) red[wave] = make_float2(mx, sm);
        __syncthreads();
        if (tid == 0) {
            float M = red[0].x, S = red[0].y;
            for (int i = 1; i < 4; ++i) {
                float nm = fmaxf(M, red[i].x);
                S = S * __expf(M - nm) + red[i].y * __expf(red[i].x - nm);
                M = nm;
            }
            lse[t] = M + __logf(S);
        }
    } else if (blk < TTC + 2) {
        int side = blk - TTC;
        const float* S = side ? rightS : leftS;
        int q = tid;
        if (q >= NTC) return;
        float mx = -FINF;
        for (int r = 0; r < 180; ++r) mx = fmaxf(mx, S[r*NTC + q]);
        float ssum = 0.f;
        for (int r = 0; r < 180; ++r) ssum += __expf(S[r*NTC + q] - mx);
        float inv = 1.f / ssum;
        for (int r = 0; r < NTC; ++r)
            clrG[r*128 + 2*q + side] = __expf(S[r*NTC + q] - mx) * inv;
        for (int r = NTC; r < 180; ++r)
            cprG[(r-NTC)*128 + 2*q + side] = __expf(S[r*NTC + q] - mx) * inv;
    } else {
        if (tid >= 64) return;   // one wave only (shfl width 64)
        float acc = 0.f;
        if (tid < NTC) {
            const float4* rr = (const float4*)(rse + (size_t)tid * SD);
            const float4* re = (const float4*)root_emb;
            for (int k = 0; k < SD/4; ++k) acc += dot4(re[k], rr[k]);
        }
        float mx = warp_max64(tid < NTC ? acc : -FINF);
        float ssum = warp_sum64(tid < NTC ? __expf(acc - mx) : 0.f);
        if (tid < NTC) root_ls[tid] = acc - (mx + __logf(ssum));
    }
}

// ===========================================================================
// online logsumexp over a strided (L,R) pair walk, unroll 4.
// ===========================================================================
__device__ inline void onlsum(const float* pL, const float* pR,
                              int dl, int dr, int kcount,
                              float& mx, float& sm)
{
    mx = -FINF; sm = 0.f;
    int i = 0;
    for (; i + 4 <= kcount; i += 4) {
        float l0 = pL[0],    r0 = pR[0];
        float l1 = pL[dl],   r1 = pR[dr];
        float l2 = pL[2*dl], r2 = pR[2*dr];
        float l3 = pL[3*dl], r3 = pR[3*dr];
        pL += 4*dl; pR += 4*dr;
        float v0 = l0+r0, v1 = l1+r1, v2 = l2+r2, v3 = l3+r3;
        float nm = fmaxf(fmaxf(fmaxf(v0,v1), fmaxf(v2,v3)), mx);
        sm = sm * __expf(mx - nm)
           + __expf(v0-nm) + __expf(v1-nm) + __expf(v2-nm) + __expf(v3-nm);
        mx = nm;
    }
    for (; i < kcount; ++i) {
        float v = pL[0] + pR[0];
        pL += dl; pR += dr;
        float nm = fmaxf(mx, v);
        sm = sm * __expf(mx - nm) + __expf(v - nm);
        mx = nm;
    }
}

// ===========================================================================
// inside_b: identical logic to round-13 (validated), plus 36 KB LDS pad so
// total = 83968 B > 81920 -> exactly 1 block/CU (defeats 2-per-CU packing).
// ===========================================================================
__global__ __launch_bounds__(1024) void inside_b(
    const float* __restrict__ logits, const float* __restrict__ lse,
    const int* __restrict__ word,
    const float* __restrict__ clrG, const float* __restrict__ cprG,
    const float* __restrict__ root_ls,
    float* LcB, float* RcB, float* __restrict__ out)
{
    __shared__ float2 clr2[NTC * 64];   // 30 KB
    __shared__ float2 part[16 * 64];    // 8 KB
    __shared__ float  esh[16 * 128];    // 8 KB
    __shared__ float  lds_pad[9216];    // 36 KB pad -> total 83968 B
    KEEP_PAD(lds_pad);

    int b = blockIdx.x;
    int tid = threadIdx.x;
    int wave = tid >> 6, lane = tid & 63;

    const float2* cg2 = (const float2*)clrG;
    for (int i = tid; i < NTC * 64; i += 1024) clr2[i] = cg2[i];

    float* Lb = LcB + (size_t)b * TB;
    float* Rb = RcB + (size_t)b * TB;
    int p = (lane < NTC) ? lane : (NTC - 1);
    const int DL = NN * NTC;        // +2400
    const int DR = (1 - NN) * NTC;  // -2340

    // ---- w = 1 init ----
    const float2* cp2 = (const float2*)cprG;
    for (int n = wave; n < NN; n += 16) {
        int wd = word[b * NN + n];
        float u0 = logits[(size_t)lane * VV + wd] - lse[lane];
        float u1 = (lane < TTC - 64) ? logits[(size_t)(lane + 64) * VV + wd] - lse[lane + 64]
                                     : -FINF;
        float M = warp_max64(fmaxf(u0, u1));
        float* e = esh + wave * 128;
        e[lane]      = __expf(u0 - M);
        e[lane + 64] = (lane < TTC - 64) ? __expf(u1 - M) : 0.f;
        const float4* e4 = (const float4*)e;
        float aL = 0.f, aR = 0.f;
#pragma unroll 5
        for (int i = 0; i < 30; ++i) {
            float4 ev = e4[i];
            float2 c0 = cp2[(4*i+0)*64 + p];
            float2 c1 = cp2[(4*i+1)*64 + p];
            float2 c2 = cp2[(4*i+2)*64 + p];
            float2 c3 = cp2[(4*i+3)*64 + p];
            aL = fmaf(ev.x, c0.x, aL); aR = fmaf(ev.x, c0.y, aR);
            aL = fmaf(ev.y, c1.x, aL); aR = fmaf(ev.y, c1.y, aR);
            aL = fmaf(ev.z, c2.x, aL); aR = fmaf(ev.z, c2.y, aR);
            aL = fmaf(ev.w, c3.x, aL); aR = fmaf(ev.w, c3.y, aR);
        }
        if (lane < NTC) {
            int o = (NN + n) * NTC + lane;
            Lb[o] = __logf(aL) + M;
            Rb[o] = __logf(aR) + M;
        }
    }
    __syncthreads();

    // ---- widths 2..40 ----
    for (int w = 2; w <= NN; ++w) {
        int m = NN - w + 1;
        if (m >= 17) {
            for (int c0 = wave; c0 < m; c0 += 32) {
                int jA = c0, jB = c0 + 16;
                bool hasB = (jB < m);
                int jBs = hasB ? jB : jA;
                const float* LA = Lb + (NN + jA)*NTC + p;
                const float* RA = Rb + ((w-1)*NN + jA + 1)*NTC + p;
                const float* LB = Lb + (NN + jBs)*NTC + p;
                const float* RB = Rb + ((w-1)*NN + jBs + 1)*NTC + p;

                float mxA = -FINF, smA = 0.f, mxB = -FINF, smB = 0.f;
                int k = 1;
                for (; k + 1 < w; k += 2) {
                    float lA0 = LA[0],  rA0 = RA[0];
                    float lA1 = LA[DL], rA1 = RA[DR];
                    float lB0 = LB[0],  rB0 = RB[0];
                    float lB1 = LB[DL], rB1 = RB[DR];
                    LA += 2*DL; RA += 2*DR; LB += 2*DL; RB += 2*DR;
                    float vA0 = lA0+rA0, vA1 = lA1+rA1;
                    float nmA = fmaxf(mxA, fmaxf(vA0, vA1));
                    smA = smA * __expf(mxA-nmA) + __expf(vA0-nmA) + __expf(vA1-nmA);
                    mxA = nmA;
                    float vB0 = lB0+rB0, vB1 = lB1+rB1;
                    float nmB = fmaxf(mxB, fmaxf(vB0, vB1));
                    smB = smB * __expf(mxB-nmB) + __expf(vB0-nmB) + __expf(vB1-nmB);
                    mxB = nmB;
                }
                if (k < w) {
                    float vA = LA[0] + RA[0];
                    float nmA = fmaxf(mxA, vA);
                    smA = smA * __expf(mxA-nmA) + __expf(vA-nmA);
                    mxA = nmA;
                    float vB = LB[0] + RB[0];
                    float nmB = fmaxf(mxB, vB);
                    smB = smB * __expf(mxB-nmB) + __expf(vB-nmB);
                    mxB = nmB;
                }
                float betaA = __logf(smA) + mxA;
                float betaB = __logf(smB) + mxB;

                float bmA = warp_max64(betaA);
                float bmB = warp_max64(betaB);
                float* eA = esh + wave * 128;
                float* eB = eA + 64;
                eA[lane] = (lane < NTC) ? __expf(betaA - bmA) : 0.f;
                eB[lane] = (lane < NTC && hasB) ? __expf(betaB - bmB) : 0.f;
                const float4* eA4 = (const float4*)eA;
                const float4* eB4 = (const float4*)eB;
                float aLA=0.f, aRA=0.f, aLB=0.f, aRB=0.f;
#pragma unroll 5
                for (int i = 0; i < 15; ++i) {
                    float4 ea = eA4[i], eb = eB4[i];
                    float2 l0 = clr2[(4*i+0)*64 + lane];
                    float2 l1 = clr2[(4*i+1)*64 + lane];
                    float2 l2 = clr2[(4*i+2)*64 + lane];
                    float2 l3 = clr2[(4*i+3)*64 + lane];
                    aLA = fmaf(ea.x, l0.x, aLA); aRA = fmaf(ea.x, l0.y, aRA);
                    aLB = fmaf(eb.x, l0.x, aLB); aRB = fmaf(eb.x, l0.y, aRB);
                    aLA = fmaf(ea.y, l1.x, aLA); aRA = fmaf(ea.y, l1.y, aRA);
                    aLB = fmaf(eb.y, l1.x, aLB); aRB = fmaf(eb.y, l1.y, aRB);
                    aLA = fmaf(ea.z, l2.x, aLA); aRA = fmaf(ea.z, l2.y, aRA);
                    aLB = fmaf(eb.z, l2.x, aLB); aRB = fmaf(eb.z, l2.y, aRB);
                    aLA = fmaf(ea.w, l3.x, aLA); aRA = fmaf(ea.w, l3.y, aRA);
                    aLB = fmaf(eb.w, l3.x, aLB); aRB = fmaf(eb.w, l3.y, aRB);
                }
                if (lane < NTC) {
                    int oA = (w*NN + jA)*NTC + lane;
                    Lb[oA] = __logf(aLA) + bmA;
                    Rb[oA] = __logf(aRA) + bmA;
                    if (hasB) {
                        int oB = (w*NN + jB)*NTC + lane;
                        Lb[oB] = __logf(aLB) + bmB;
                        Rb[oB] = __logf(aRB) + bmB;
                    }
                }
            }
        } else if (m >= 9) {
            if (wave < m) {
                int j = wave;
                const float* pL = Lb + (NN + j)*NTC + p;
                const float* pR = Rb + ((w-1)*NN + j + 1)*NTC + p;
                float mx, sm;
                onlsum(pL, pR, DL, DR, w - 1, mx, sm);
                float beta = __logf(sm) + mx;
                float bm = warp_max64(beta);
                float* e = esh + wave * 128;
                e[lane] = (lane < NTC) ? __expf(beta - bm) : 0.f;
                const float4* e4 = (const float4*)e;
                float aL = 0.f, aR = 0.f;
#pragma unroll 5
                for (int i = 0; i < 15; ++i) {
                    float4 ev = e4[i];
                    float2 l0 = clr2[(4*i+0)*64 + lane];
                    float2 l1 = clr2[(4*i+1)*64 + lane];
                    float2 l2 = clr2[(4*i+2)*64 + lane];
                    float2 l3 = clr2[(4*i+3)*64 + lane];
                    aL = fmaf(ev.x, l0.x, aL); aR = fmaf(ev.x, l0.y, aR);
                    aL = fmaf(ev.y, l1.x, aL); aR = fmaf(ev.y, l1.y, aR);
                    aL = fmaf(ev.z, l2.x, aL); aR = fmaf(ev.z, l2.y, aR);
                    aL = fmaf(ev.w, l3.x, aL); aR = fmaf(ev.w, l3.y, aR);
                }
                if (lane < NTC) {
                    int o = (w*NN + j)*NTC + lane;
                    Lb[o] = __logf(aL) + bm;
                    Rb[o] = __logf(aR) + bm;
                }
            }
        } else {
            int G = 16 / m;
            if (wave < G * m) {
                int c = wave % m, g = wave / m;
                int k0 = 1 + g;
                const float* pL = Lb + (k0*NN + c)*NTC + p;
                const float* pR = Rb + ((w-k0)*NN + c + k0)*NTC + p;
                int kcount = (w - k0 + G - 1) / G;
                float mx, sm;
                onlsum(pL, pR, G*DL, G*DR, kcount, mx, sm);
                part[tid >> 6 << 6 | lane] = make_float2(mx, sm);
            }
            __syncthreads();
            if (wave < m) {
                int c = wave;
                float mx = -FINF, sm = 0.f;
                for (int g = 0; g < G; ++g) {
                    float2 pr = part[(g*m + c)*64 + lane];
                    float nm = fmaxf(mx, pr.x);
                    sm = sm * __expf(mx - nm) + pr.y * __expf(pr.x - nm);
                    mx = nm;
                }
                float beta = __logf(sm) + mx;
                if (w == NN) {
                    float v = (lane < NTC) ? root_ls[lane] + beta : -FINF;
                    float vm = warp_max64(v);
                    float vs = warp_sum64(lane < NTC ? __expf(v - vm) : 0.f);
                    if (lane == 0) out[b] = vm + __logf(vs);
                } else {
                    float bm = warp_max64(beta);
                    float* e = esh + wave * 128;
                    e[lane] = (lane < NTC) ? __expf(beta - bm) : 0.f;
                    const float4* e4 = (const float4*)e;
                    float aL = 0.f, aR = 0.f;
#pragma unroll 5
                    for (int i = 0; i < 15; ++i) {
                        float4 ev = e4[i];
                        float2 l0 = clr2[(4*i+0)*64 + lane];
                        float2 l1 = clr2[(4*i+1)*64 + lane];
                        float2 l2 = clr2[(4*i+2)*64 + lane];
                        float2 l3 = clr2[(4*i+3)*64 + lane];
                        aL = fmaf(ev.x, l0.x, aL); aR = fmaf(ev.x, l0.y, aR);
                        aL = fmaf(ev.y, l1.x, aL); aR = fmaf(ev.y, l1.y, aR);
                        aL = fmaf(ev.z, l2.x, aL); aR = fmaf(ev.z, l2.y, aR);
                        aL = fmaf(ev.w, l3.x, aL); aR = fmaf(ev.w, l3.y, aR);
                    }
                    if (lane < NTC) {
                        int o = (w*NN + c)*NTC + lane;
                        Lb[o] = __logf(aL) + bm;
                        Rb[o] = __logf(aR) + bm;
                    }
                }
            }
        }
        __syncthreads();
    }
}

// ===========================================================================
// loss = -mean(partition)
// ===========================================================================
__global__ __launch_bounds__(64) void mean_k(float* out)
{
    int lane = threadIdx.x;
    float s = out[lane] + out[lane + 64];
    s = warp_sum64(s);
    if (lane == 0) out[BB] = -s / (float)BB;
}

// ===========================================================================
extern "C" void kernel_launch(void* const* d_in, const int* in_sizes, int n_in,
                              void* d_out, int out_size, void* d_ws, size_t ws_size,
                              hipStream_t stream)
{
    const int*   word     = (const int*)  d_in[0];
    const float* root_emb = (const float*)d_in[1];
    const float* rse      = (const float*)d_in[2];   // (180, 512)
    const float* VE       = (const float*)d_in[3];   // (512, 10000)
    const float* W0       = (const float*)d_in[4];
    const float* b0       = (const float*)d_in[5];
    const float* W1       = (const float*)d_in[6];   // (3,512,512)
    const float* b1       = (const float*)d_in[7];
    const float* W2       = (const float*)d_in[8];
    const float* b2       = (const float*)d_in[9];
    const float* lW       = (const float*)d_in[10];
    const float* lb       = (const float*)d_in[11];
    const float* rW       = (const float*)d_in[12];
    const float* rb       = (const float*)d_in[13];
    const float* pW       = (const float*)d_in[14];
    const float* pb       = (const float*)d_in[15];

    float* ws = (float*)d_ws;
    size_t o = 0;
    float* logits  = ws + o; o += (size_t)TTC * VV;     // 1,200,000
    float* lse     = ws + o; o += 128;
    float* gbuf    = ws + o; o += TTC * SD;
    float* parent1 = ws + o; o += NTC * SD;
    float* leftH   = ws + o; o += 180 * SD;
    float* rightH  = ws + o; o += 180 * SD;
    float* leftS   = ws + o; o += 180 * NTC;
    float* rightS  = ws + o; o += 180 * NTC;
    float* clrG    = ws + o; o += NTC * 128;
    float* cprG    = ws + o; o += TTC * 128;
    float* root_ls = ws + o; o += 64;
    float* LcB     = ws + o; o += (size_t)BB * TB;      // 12,288,000
    float* RcB     = ws + o; o += (size_t)BB * TB;

    grammar_A<<<540, 512, 0, stream>>>(rse, W0, b0, W1, b1, W2, b2,
                                       lW, lb, rW, rb, pW, pb,
                                       gbuf, parent1, leftH, rightH);
    vb_k<<<285, 256, 0, stream>>>(gbuf, VE, logits, leftH, rightH, parent1,
                                  leftS, rightS);
    lc_k<<<123, 256, 0, stream>>>(logits, lse, leftS, rightS, root_emb, rse,
                                  clrG, cprG, root_ls);
    inside_b<<<BB, 1024, 0, stream>>>(logits, lse, word, clrG, cprG, root_ls,
                                      LcB, RcB, (float*)d_out);
    mean_k<<<1, 64, 0, stream>>>((float*)d_out);
}